// Round 6
// baseline (89.088 us; speedup 1.0000x reference)
//
#include <hip/hip_runtime.h>
#include <math.h>

#define BB 64          // batch
#define CC 16          // children per sample
#define DD 512         // feature dim
#define LL 8192        // CC*DD flattened length
#define EPSV 1e-8f
#define INVT 10.0f     // 1/TEMPERATURE
#define NEGINF_T (-1e31f)   // NEG_INF / TEMPERATURE

// ws layout (float offsets):
//  [0,1024)    n2i : ||ci row r||^2 (exact fp32)
//  [1024,2048) n2j : ||cj row r||^2 (exact fp32)
//  [2048,2112) pos : exact fp32 dot(fi,fj)
//  WS_THI: T_hi bf16[2048][512]  (rows 0-1023 = cj, 1024-2047 = ci)
//  WS_TLO: T_lo bf16[2048][512]  (residual after hi)
//  WS_G  : G fp32 [1024][2048] = ci_rows · T_rows^T  (all pair dots)
#define WS_N2I 0
#define WS_N2J 1024
#define WS_POS 2048
#define WS_THI 4096
#define WS_TLO (4096 + 524288)
#define WS_G   (4096 + 1048576)

typedef short bf16x8 __attribute__((ext_vector_type(8)));
typedef float f32x4  __attribute__((ext_vector_type(4)));

__device__ __forceinline__ float dot4(float4 a, float4 b) {
    return a.x * b.x + a.y * b.y + a.z * b.z + a.w * b.w;
}

__device__ __forceinline__ float wave_reduce(float v) {
    #pragma unroll
    for (int off = 32; off; off >>= 1) v += __shfl_down(v, off);
    return v;
}

__device__ __forceinline__ ushort f2bf(float x) {           // RN-even fp32->bf16
    unsigned u = __float_as_uint(x);
    return (ushort)((u + 0x7FFFu + ((u >> 16) & 1u)) >> 16);
}

__device__ __forceinline__ void split4(float4 v, ushort4& h, ushort4& l) {
    h.x = f2bf(v.x); h.y = f2bf(v.y); h.z = f2bf(v.z); h.w = f2bf(v.w);
    l.x = f2bf(v.x - __uint_as_float((unsigned)h.x << 16));
    l.y = f2bf(v.y - __uint_as_float((unsigned)h.y << 16));
    l.z = f2bf(v.z - __uint_as_float((unsigned)h.z << 16));
    l.w = f2bf(v.w - __uint_as_float((unsigned)h.w << 16));
}

// LDS tile [rows][32] bf16, 64B rows. XOR-swizzle bits 4-5 by row bits 1-2:
// puts exactly 2 lanes/bank for both the staging write and the fragment read.
__device__ __forceinline__ int lds_addr(int row, int q) {
    int a = (row << 6) + (q << 4);
    return a ^ ((row & 6) << 3);
}

// ---------------------------------------------------------------------------
// convert: blocks [0,512): 4 T-rows each (1 wave = 1 row). Splits each row
//          into bf16 hi/lo (RN), writes T_hi/T_lo, and computes the EXACT
//          fp32 row norm (n2j for rows<1024=cj, n2i for rows>=1024=ci).
//          blocks [512,576): exact fp32 positive dot for anchor b-512;
//          b==512 zeroes out[0].
// ---------------------------------------------------------------------------
__global__ __launch_bounds__(256) void ntx_convert(const float* __restrict__ ci,
                                                   const float* __restrict__ cj,
                                                   float* __restrict__ ws,
                                                   float* __restrict__ out) {
    const int b = blockIdx.x, tid = threadIdx.x;
    if (b < 512) {
        const int g    = b * 4 + (tid >> 6);   // T row 0..2047
        const int lane = tid & 63;
        const float* srow = (g < 1024) ? (cj + g * DD) : (ci + (g - 1024) * DD);
        float4 v1 = ((const float4*)srow)[lane];
        float4 v2 = ((const float4*)srow)[64 + lane];

        float acc = dot4(v1, v1) + dot4(v2, v2);
        acc = wave_reduce(acc);
        if (lane == 0) ws[g < 1024 ? (WS_N2J + g) : (WS_N2I + (g - 1024))] = acc;

        ushort4 h1, l1, h2, l2;
        split4(v1, h1, l1);
        split4(v2, h2, l2);
        ushort* thi = (ushort*)(ws + WS_THI);
        ushort* tlo = (ushort*)(ws + WS_TLO);
        ((ushort4*)(thi + g * DD))[lane]       = h1;
        ((ushort4*)(thi + g * DD + 256))[lane] = h2;
        ((ushort4*)(tlo + g * DD))[lane]       = l1;
        ((ushort4*)(tlo + g * DD + 256))[lane] = l2;
    } else {
        __shared__ float red2[4];
        const int i = b - 512;
        if (b == 512 && tid == 0) out[0] = 0.f;
        const float4* fi = (const float4*)(ci + i * LL);
        const float4* fj = (const float4*)(cj + i * LL);
        float acc = 0.f;
        #pragma unroll
        for (int it = 0; it < 8; ++it) acc += dot4(fi[tid + 256 * it], fj[tid + 256 * it]);
        acc = wave_reduce(acc);
        if ((tid & 63) == 0) red2[tid >> 6] = acc;
        __syncthreads();
        if (tid == 0) ws[WS_POS + i] = red2[0] + red2[1] + red2[2] + red2[3];
    }
}

// ---------------------------------------------------------------------------
// gemm: G[m,n] = sum_d ci_row[m][d] * T_row[n][d], M=1024, N=2048, K=512.
//   bf16 hi/lo 3-product split (hi*hi + hi*lo + lo*hi) -> ~fp32 accuracy.
//   256 blocks: bm=blk&7 (128 A-rows), bn=blk>>3 (64 T-rows). 4 waves in 2x2,
//   each wave 64x32 output = 4x2 frags of 16x16. K-loop 16 steps of 32.
//   Both operands loaded with the SAME lane->offset pattern (8 consecutive
//   bf16 at k=(lane>>4)*8, row=lane&15) so any internal k-ordering of the
//   MFMA cancels in the Gram dot; C/D mapping is the HW-verified
//   col=lane&15, row=(lane>>4)*4+reg.
// ---------------------------------------------------------------------------
__global__ __launch_bounds__(256) void ntx_gemm(float* __restrict__ ws) {
    const ushort* Thi = (const ushort*)(ws + WS_THI);
    const ushort* Tlo = (const ushort*)(ws + WS_TLO);
    float* G = ws + WS_G;

    __shared__ __align__(16) ushort sAhi[128 * 32];
    __shared__ __align__(16) ushort sAlo[128 * 32];
    __shared__ __align__(16) ushort sBhi[64 * 32];
    __shared__ __align__(16) ushort sBlo[64 * 32];

    const int tid  = threadIdx.x;
    const int bm   = blockIdx.x & 7;
    const int bn   = blockIdx.x >> 3;
    const int lane = tid & 63, wid = tid >> 6;
    const int wm   = wid >> 1, wn = wid & 1;

    // staging: A-tile 128x32 (512 x 16B chunks: tid and tid+256), B-tile 64x32 (256 chunks)
    const int rowA0 = tid >> 2, qA = tid & 3;
    const int rowB  = tid >> 2, qB = tid & 3;
    const int gA0 = (1024 + bm * 128 + rowA0) * DD + qA * 8;
    const int gA1 = gA0 + 64 * DD;
    const int gB  = (bn * 64 + rowB) * DD + qB * 8;
    const int aA0 = lds_addr(rowA0, qA), aA1 = lds_addr(rowA0 + 64, qA);
    const int aB  = lds_addr(rowB, qB);

    // fragment read addrs
    int fA[4], fB[2];
    #pragma unroll
    for (int fm = 0; fm < 4; ++fm) fA[fm] = lds_addr(wm * 64 + fm * 16 + (lane & 15), lane >> 4);
    #pragma unroll
    for (int fn = 0; fn < 2; ++fn) fB[fn] = lds_addr(wn * 32 + fn * 16 + (lane & 15), lane >> 4);

    f32x4 acc[4][2] = {};
    float4 pAh0, pAh1, pAl0, pAl1, pBh, pBl;

    #define LOADSTEP(KS) { const int off = (KS) * 32;                       \
        pAh0 = *(const float4*)(Thi + gA0 + off);                           \
        pAh1 = *(const float4*)(Thi + gA1 + off);                           \
        pAl0 = *(const float4*)(Tlo + gA0 + off);                           \
        pAl1 = *(const float4*)(Tlo + gA1 + off);                           \
        pBh  = *(const float4*)(Thi + gB  + off);                           \
        pBl  = *(const float4*)(Tlo + gB  + off); }

    LOADSTEP(0);
    for (int ks = 0; ks < 16; ++ks) {
        __syncthreads();
        *(float4*)((char*)sAhi + aA0) = pAh0;
        *(float4*)((char*)sAhi + aA1) = pAh1;
        *(float4*)((char*)sAlo + aA0) = pAl0;
        *(float4*)((char*)sAlo + aA1) = pAl1;
        *(float4*)((char*)sBhi + aB)  = pBh;
        *(float4*)((char*)sBlo + aB)  = pBl;
        __syncthreads();
        if (ks < 15) LOADSTEP(ks + 1);

        bf16x8 ah[4], al[4], bh[2], bl[2];
        #pragma unroll
        for (int fm = 0; fm < 4; ++fm) {
            ah[fm] = *(const bf16x8*)((const char*)sAhi + fA[fm]);
            al[fm] = *(const bf16x8*)((const char*)sAlo + fA[fm]);
        }
        #pragma unroll
        for (int fn = 0; fn < 2; ++fn) {
            bh[fn] = *(const bf16x8*)((const char*)sBhi + fB[fn]);
            bl[fn] = *(const bf16x8*)((const char*)sBlo + fB[fn]);
        }
        #pragma unroll
        for (int fm = 0; fm < 4; ++fm)
            #pragma unroll
            for (int fn = 0; fn < 2; ++fn) {
                acc[fm][fn] = __builtin_amdgcn_mfma_f32_16x16x32_bf16(ah[fm], bh[fn], acc[fm][fn], 0, 0, 0);
                acc[fm][fn] = __builtin_amdgcn_mfma_f32_16x16x32_bf16(ah[fm], bl[fn], acc[fm][fn], 0, 0, 0);
                acc[fm][fn] = __builtin_amdgcn_mfma_f32_16x16x32_bf16(al[fm], bh[fn], acc[fm][fn], 0, 0, 0);
            }
    }
    #undef LOADSTEP

    const int r0 = bm * 128 + wm * 64 + (lane >> 4) * 4;
    const int c0 = bn * 64 + wn * 32 + (lane & 15);
    #pragma unroll
    for (int fm = 0; fm < 4; ++fm)
        #pragma unroll
        for (int fn = 0; fn < 2; ++fn)
            #pragma unroll
            for (int r = 0; r < 4; ++r)
                G[(r0 + fm * 16 + r) * 2048 + c0 + fn * 16] = acc[fm][fn][r];
}

// ---------------------------------------------------------------------------
// final: block i, lane j. Raw dots = 16-entry sums over G; normalize with the
// exact n2 sums; masked logsumexp over 129 logits; atomicAdd loss_i/(2B).
// ---------------------------------------------------------------------------
__global__ __launch_bounds__(64) void ntx_final(const int* __restrict__ pids,
                                                const int* __restrict__ nj,
                                                const int* __restrict__ nk,
                                                const float* __restrict__ ws,
                                                float* __restrict__ out) {
    const int i = blockIdx.x, j = threadIdx.x;
    __shared__ float sn2i[1024], sn2j[1024];
    const float4* n2i4 = (const float4*)(ws + WS_N2I);
    const float4* n2j4 = (const float4*)(ws + WS_N2J);
    #pragma unroll
    for (int t = 0; t < 4; ++t) {
        ((float4*)sn2i)[j + 64 * t] = n2i4[j + 64 * t];
        ((float4*)sn2j)[j + 64 * t] = n2j4[j + 64 * t];
    }
    __syncthreads();

    float si = 0.f, sjf = 0.f;
    #pragma unroll
    for (int c = 0; c < CC; ++c) { si += sn2i[i * CC + c]; sjf += sn2j[i * CC + c]; }
    const float ni = fmaxf(sqrtf(si), EPSV);
    const float l0 = ws[WS_POS + i] / (ni * fmaxf(sqrtf(sjf), EPSV)) * INVT;

    const float* G = ws + WS_G;
    const int gbase = (i * CC) * 2048 + j * CC;   // G[i*16][j*16]

    const int4* nj4 = (const int4*)(nj + (i * BB + j) * CC);
    const int4* nk4 = (const int4*)(nk + (i * BB + j) * CC);
    float gj = 0.f, gk = 0.f, rawj = 0.f, rawk = 0.f;
    #pragma unroll
    for (int t = 0; t < 4; ++t) {
        int4 a = nj4[t];
        gj   += sn2j[j * CC + a.x] + sn2j[j * CC + a.y] + sn2j[j * CC + a.z] + sn2j[j * CC + a.w];
        rawj += G[gbase + (4 * t + 0) * 2048 + a.x] + G[gbase + (4 * t + 1) * 2048 + a.y]
              + G[gbase + (4 * t + 2) * 2048 + a.z] + G[gbase + (4 * t + 3) * 2048 + a.w];
        int4 bq = nk4[t];
        gk   += sn2i[j * CC + bq.x] + sn2i[j * CC + bq.y] + sn2i[j * CC + bq.z] + sn2i[j * CC + bq.w];
        rawk += G[gbase + 1024 + (4 * t + 0) * 2048 + bq.x] + G[gbase + 1024 + (4 * t + 1) * 2048 + bq.y]
              + G[gbase + 1024 + (4 * t + 2) * 2048 + bq.z] + G[gbase + 1024 + (4 * t + 3) * 2048 + bq.w];
    }

    const bool valid = (j != i) && (pids[j] != pids[i]);
    float lj = NEGINF_T, lk = NEGINF_T;
    if (valid) {
        const float inv = INVT / ni;
        lj = rawj / fmaxf(sqrtf(gj), EPSV) * inv;
        lk = rawk / fmaxf(sqrtf(gk), EPSV) * inv;
    }

    float m = fmaxf(lj, lk);
    #pragma unroll
    for (int off = 32; off; off >>= 1) m = fmaxf(m, __shfl_xor(m, off));
    m = fmaxf(m, l0);

    float s = __expf(lj - m) + __expf(lk - m);
    s = wave_reduce(s);
    if (j == 0) {
        s += __expf(l0 - m);
        const float loss_i = -l0 + m + __logf(s);
        atomicAdd(out, loss_i * (1.0f / (2.0f * BB)));
    }
}

// ---------------------------------------------------------------------------
extern "C" void kernel_launch(void* const* d_in, const int* in_sizes, int n_in,
                              void* d_out, int out_size, void* d_ws, size_t ws_size,
                              hipStream_t stream) {
    const float* ci  = (const float*)d_in[0];
    const float* cj  = (const float*)d_in[1];
    const int*  pids = (const int*) d_in[2];
    const int*  nj   = (const int*) d_in[3];
    const int*  nk   = (const int*) d_in[4];
    float* ws  = (float*)d_ws;
    float* out = (float*)d_out;

    ntx_convert<<<576, 256, 0, stream>>>(ci, cj, ws, out);
    ntx_gemm<<<256, 256, 0, stream>>>(ws);
    ntx_final<<<BB, 64, 0, stream>>>(pids, nj, nk, ws, out);
}

// Round 7
// 76.622 us; speedup vs baseline: 1.1627x; 1.1627x over previous
//
#include <hip/hip_runtime.h>
#include <math.h>

#define BB 64          // batch
#define CC 16          // children per sample
#define DD 512         // feature dim
#define LL 8192        // CC*DD flattened length
#define EPSV 1e-8f
#define INVT 10.0f     // 1/TEMPERATURE

// ws layout (floats):
//  [0,1024)    esum : per-(anchor, jt) partial sum of exp(logit) over the
//                     4 j's x 2 sides handled by sim block (i,jt)
//  [1024,1088) l0   : positive logit per anchor (already /T)
#define WS_ESUM 0
#define WS_L0   1024

__device__ __forceinline__ float dot4(float4 a, float4 b) {
    return a.x * b.x + a.y * b.y + a.z * b.z + a.w * b.w;
}

__device__ __forceinline__ float wave_reduce(float v) {
    #pragma unroll
    for (int off = 32; off; off >>= 1) v += __shfl_down(v, off);
    return v;
}

// ---------------------------------------------------------------------------
// main — every block fully self-contained (no cross-role data flow):
//   blocks [0,1024): sim role (r1's proven gather structure, jt=b&15, i=b>>4,
//     4 j's per block). NEW vs r1: gathered-row norms and the anchor norm are
//     accumulated as dot4(v,v) on data already in registers (free — replaces
//     the 512 norm-role blocks and their 8MB of reads), and the epilogue
//     finishes the logits to exp() locally (logits bounded by ±10 -> no max
//     subtraction needed) writing ONE esum partial per block.
//   blocks [1024,1088): pos role, anchor i=b-1024: l0 = cos(fi,fj)/T,
//     all three reductions self-computed. Writes ws[WS_L0+i].
//   No atomics, no out zero-init, no ordering assumptions.
// ---------------------------------------------------------------------------
__global__ __launch_bounds__(256) void ntx_main(const float* __restrict__ ci,
                                                const float* __restrict__ cj,
                                                const int* __restrict__ pids,
                                                const int* __restrict__ nj,
                                                const int* __restrict__ nk,
                                                float* __restrict__ ws) {
    const int b = blockIdx.x, tid = threadIdx.x;

    if (b < 1024) {
        // ---- sim role ----
        __shared__ int   sidx[2][4][16];     // [side][jj][c]
        __shared__ float red[4][4][4];       // [jj][{aj,ak,gj,gk}][wave]
        __shared__ float nred[4];            // anchor-norm partials per wave
        const int jt = b & 15;    // 0..15
        const int i  = b >> 4;    // 0..63

        if (tid < 64)        ((int*)sidx)[tid] = nj[i * 1024 + jt * 64 + tid];
        else if (tid < 128)  ((int*)sidx)[tid] = nk[i * 1024 + jt * 64 + (tid - 64)];

        const float4* fi4 = (const float4*)(ci + i * LL);
        float4 fiv[8];
        float nacc = 0.f;
        #pragma unroll
        for (int it = 0; it < 8; ++it) {
            fiv[it] = fi4[tid + 256 * it];
            nacc += dot4(fiv[it], fiv[it]);
        }

        __syncthreads();

        const int d4   = tid & 127;   // float4 offset within a child row
        const int half = tid >> 7;    // c parity handled by this half
        const int wave = tid >> 6;
        const float4* cj4 = (const float4*)cj;
        const float4* ci4 = (const float4*)ci;

        {
            float nr = wave_reduce(nacc);
            if ((tid & 63) == 0) nred[wave] = nr;
        }

        #pragma unroll
        for (int jj = 0; jj < 4; ++jj) {
            const int j = jt * 4 + jj;
            const float4* bj = cj4 + j * CC * 128;
            const float4* bk = ci4 + j * CC * 128;
            float aj = 0.f, ak = 0.f, gj = 0.f, gk = 0.f;
            #pragma unroll
            for (int it = 0; it < 8; ++it) {
                const int c = half + 2 * it;           // (tid + it*256) >> 7
                float4 vj = bj[sidx[0][jj][c] * 128 + d4];
                float4 vk = bk[sidx[1][jj][c] * 128 + d4];
                aj += dot4(fiv[it], vj);
                gj += dot4(vj, vj);
                ak += dot4(fiv[it], vk);
                gk += dot4(vk, vk);
            }
            aj = wave_reduce(aj);
            ak = wave_reduce(ak);
            gj = wave_reduce(gj);
            gk = wave_reduce(gk);
            if ((tid & 63) == 0) {
                red[jj][0][wave] = aj; red[jj][1][wave] = ak;
                red[jj][2][wave] = gj; red[jj][3][wave] = gk;
            }
        }
        __syncthreads();
        if (tid < 4) {
            const int jj = tid, j = jt * 4 + jj;
            const float aj = red[jj][0][0] + red[jj][0][1] + red[jj][0][2] + red[jj][0][3];
            const float ak = red[jj][1][0] + red[jj][1][1] + red[jj][1][2] + red[jj][1][3];
            const float gj = red[jj][2][0] + red[jj][2][1] + red[jj][2][2] + red[jj][2][3];
            const float gk = red[jj][3][0] + red[jj][3][1] + red[jj][3][2] + red[jj][3][3];
            const float si = nred[0] + nred[1] + nred[2] + nred[3];
            const float ni = fmaxf(sqrtf(si), EPSV);
            float e = 0.f;
            if ((j != i) && (pids[j] != pids[i])) {
                const float inv = INVT / ni;
                const float lj = aj / fmaxf(sqrtf(gj), EPSV) * inv;   // in [-10,10]
                const float lk = ak / fmaxf(sqrtf(gk), EPSV) * inv;
                e = __expf(lj) + __expf(lk);                          // <= 4.5e4, safe
            }
            e += __shfl_xor(e, 1);
            e += __shfl_xor(e, 2);
            if (jj == 0) ws[WS_ESUM + i * 16 + jt] = e;
        }
    } else {
        // ---- pos role ----
        __shared__ float pr[3][4];
        const int i = b - 1024;
        const float4* fi = (const float4*)(ci + i * LL);
        const float4* fj = (const float4*)(cj + i * LL);
        float d = 0.f, a2 = 0.f, b2 = 0.f;
        #pragma unroll
        for (int it = 0; it < 8; ++it) {
            float4 u = fi[tid + 256 * it];
            float4 v = fj[tid + 256 * it];
            d  += dot4(u, v);
            a2 += dot4(u, u);
            b2 += dot4(v, v);
        }
        d  = wave_reduce(d);
        a2 = wave_reduce(a2);
        b2 = wave_reduce(b2);
        if ((tid & 63) == 0) { pr[0][tid >> 6] = d; pr[1][tid >> 6] = a2; pr[2][tid >> 6] = b2; }
        __syncthreads();
        if (tid == 0) {
            const float dd = pr[0][0] + pr[0][1] + pr[0][2] + pr[0][3];
            const float ia = pr[1][0] + pr[1][1] + pr[1][2] + pr[1][3];
            const float jb = pr[2][0] + pr[2][1] + pr[2][2] + pr[2][3];
            ws[WS_L0 + i] = dd / (fmaxf(sqrtf(ia), EPSV) * fmaxf(sqrtf(jb), EPSV)) * INVT;
        }
    }
}

// ---------------------------------------------------------------------------
// fin: ONE block, 256 threads. 4 threads per anchor sum the 16 esum partials
// (float4 loads), lane0-of-4 adds exp(l0) and takes the log (no max needed:
// all logits bounded by |10|), then one wave reduces the 64 per-anchor terms
// and writes out[0] directly (no atomic, no zero-init).
// ---------------------------------------------------------------------------
__global__ __launch_bounds__(256) void ntx_fin(const float* __restrict__ ws,
                                               float* __restrict__ out) {
    const int tid = threadIdx.x;
    const int i = tid >> 2, p = tid & 3;
    float4 v4 = *(const float4*)(ws + WS_ESUM + i * 16 + p * 4);
    float v = v4.x + v4.y + v4.z + v4.w;
    v += __shfl_xor(v, 1);
    v += __shfl_xor(v, 2);
    __shared__ float terms[64];
    if ((tid & 3) == 0) {
        const float l0 = ws[WS_L0 + i];
        terms[i] = -l0 + __logf(v + __expf(l0));
    }
    __syncthreads();
    if (tid < 64) {
        float t = terms[tid];
        t = wave_reduce(t);
        if (tid == 0) out[0] = t * (1.0f / (2.0f * BB));
    }
}

// ---------------------------------------------------------------------------
extern "C" void kernel_launch(void* const* d_in, const int* in_sizes, int n_in,
                              void* d_out, int out_size, void* d_ws, size_t ws_size,
                              hipStream_t stream) {
    const float* ci  = (const float*)d_in[0];
    const float* cj  = (const float*)d_in[1];
    const int*  pids = (const int*) d_in[2];
    const int*  nj   = (const int*) d_in[3];
    const int*  nk   = (const int*) d_in[4];
    float* ws  = (float*)d_ws;
    float* out = (float*)d_out;

    ntx_main<<<1088, 256, 0, stream>>>(ci, cj, pids, nj, nk, ws);
    ntx_fin<<<1, 256, 0, stream>>>(ws, out);
}